// Round 1
// baseline (158347.375 us; speedup 1.0000x reference)
//
#include <hip/hip_runtime.h>
#include <hip/hip_cooperative_groups.h>

namespace cg = cooperative_groups;

typedef _Float16 h2 __attribute__((ext_vector_type(2)));

static constexpr int T_LEN = 1024;
static constexpr int RD    = 8192;
static constexpr int SD    = 128;

// ---------- fdot2 wrapper: v_dot2_f32_f16 with scalar fallback ----------
__device__ __forceinline__ float dot2(unsigned int a, unsigned int b, float c) {
#if __has_builtin(__builtin_amdgcn_fdot2)
  return __builtin_amdgcn_fdot2(__builtin_bit_cast(h2, a), __builtin_bit_cast(h2, b), c, false);
#else
  h2 ha = __builtin_bit_cast(h2, a), hb = __builtin_bit_cast(h2, b);
  return c + (float)ha[0] * (float)hb[0] + (float)ha[1] * (float)hb[1];
#endif
}

// ---------- W_res fp32 -> fp16 (ushort bits), grid-stride float4 ----------
__global__ void cvt_w_kernel(const float* __restrict__ w, unsigned short* __restrict__ w16, long n) {
  long i = ((long)blockIdx.x * blockDim.x + threadIdx.x) * 4;
  long stride = (long)gridDim.x * blockDim.x * 4;
  for (; i < n; i += stride) {
    float4 f = *(const float4*)(w + i);
    h2 p0 = { (_Float16)f.x, (_Float16)f.y };
    h2 p1 = { (_Float16)f.z, (_Float16)f.w };
    uint2 o;
    o.x = __builtin_bit_cast(unsigned int, p0);
    o.y = __builtin_bit_cast(unsigned int, p1);
    *(uint2*)(w16 + i) = o;
  }
}

// ---------- r0 fp32 -> fp16 ----------
__global__ void cvt_r16_kernel(const float* __restrict__ r, unsigned short* __restrict__ rh) {
  int i = blockIdx.x * 256 + threadIdx.x;
  _Float16 h = (_Float16)r[i];
  rh[i] = __builtin_bit_cast(unsigned short, h);
}

// ---------- r0 fp32 -> fp32 (fallback path) ----------
__global__ void cvt_r32_kernel(const float* __restrict__ r, float* __restrict__ rf) {
  int i = blockIdx.x * 256 + threadIdx.x;
  rf[i] = r[i];
}

// ---------- in_proj = in_seq @ W_in^T + b_res, written into d_out ----------
// grid (32 i-blocks, 128 t-blocks), block 256. Block handles 256 i x 8 t.
__global__ void in_proj_kernel(const float* __restrict__ in_seq,  // 1024 x 128
                               const float* __restrict__ W_in,    // 8192 x 128
                               const float* __restrict__ b_res,   // 8192
                               float* __restrict__ out) {         // 1024 x 8192
  __shared__ float u[8 * SD];
  const int tid = threadIdx.x;
  const int ib = blockIdx.x;
  const int tb = blockIdx.y;
  ((float4*)u)[tid] = ((const float4*)(in_seq + (size_t)tb * 8 * SD))[tid];
  __syncthreads();
  const int i = ib * 256 + tid;
  const float4* wrow = (const float4*)(W_in + (size_t)i * SD);
  float b = b_res[i];
  float acc[8];
#pragma unroll
  for (int t = 0; t < 8; ++t) acc[t] = b;
  for (int kc = 0; kc < SD / 4; ++kc) {
    float4 w = wrow[kc];
#pragma unroll
    for (int t = 0; t < 8; ++t) {
      float4 uv = ((const float4*)(u + t * SD))[kc];
      acc[t] += w.x * uv.x + w.y * uv.y + w.z * uv.z + w.w * uv.w;
    }
  }
#pragma unroll
  for (int t = 0; t < 8; ++t)
    out[(size_t)(tb * 8 + t) * RD + i] = acc[t];
}

// ---------- persistent cooperative rollout ----------
// 256 blocks x 1024 threads. Block owns 32 rows; each wave owns 2 adjacent rows.
// rbuf double-buffers the state (fp16 or fp32). io holds in_proj on entry,
// res_seq on exit (in-place per element).
template <bool FP16>
__global__ __launch_bounds__(1024) void rollout_kernel(const void* __restrict__ Wv,
                                                       void* __restrict__ rbuf,
                                                       float* __restrict__ io) {
  cg::grid_group grid = cg::this_grid();
  const int lane = threadIdx.x & 63;
  const int wave = threadIdx.x >> 6;
  const int row0 = blockIdx.x * 32 + wave * 2;

  for (int t = 0; t < T_LEN; ++t) {
    float a0 = 0.f, a1 = 0.f;
    if constexpr (FP16) {
      const uint4* w0 = (const uint4*)((const unsigned short*)Wv + (size_t)row0 * RD);
      const uint4* w1 = w0 + RD / 8;
      const uint4* rh = (const uint4*)((const unsigned short*)rbuf + (size_t)(t & 1) * RD);
#pragma unroll 4
      for (int j = 0; j < 16; ++j) {
        int idx = j * 64 + lane;
        uint4 rv = rh[idx];
        uint4 wa = w0[idx];
        uint4 wb = w1[idx];
        a0 = dot2(wa.x, rv.x, a0); a0 = dot2(wa.y, rv.y, a0);
        a0 = dot2(wa.z, rv.z, a0); a0 = dot2(wa.w, rv.w, a0);
        a1 = dot2(wb.x, rv.x, a1); a1 = dot2(wb.y, rv.y, a1);
        a1 = dot2(wb.z, rv.z, a1); a1 = dot2(wb.w, rv.w, a1);
      }
    } else {
      const float4* w0 = (const float4*)((const float*)Wv + (size_t)row0 * RD);
      const float4* w1 = w0 + RD / 4;
      const float4* rf = (const float4*)((const float*)rbuf + (size_t)(t & 1) * RD);
#pragma unroll 2
      for (int j = 0; j < 32; ++j) {
        int idx = j * 64 + lane;
        float4 rv = rf[idx];
        float4 wa = w0[idx];
        float4 wb = w1[idx];
        a0 += wa.x * rv.x + wa.y * rv.y + wa.z * rv.z + wa.w * rv.w;
        a1 += wb.x * rv.x + wb.y * rv.y + wb.z * rv.z + wb.w * rv.w;
      }
    }
#pragma unroll
    for (int off = 32; off; off >>= 1) {
      a0 += __shfl_xor(a0, off);
      a1 += __shfl_xor(a1, off);
    }
    if (lane == 0) {
      float2 p = *(const float2*)(io + (size_t)t * RD + row0);
      float v0 = tanhf(a0 + p.x);
      float v1 = tanhf(a1 + p.y);
      *(float2*)(io + (size_t)t * RD + row0) = make_float2(v0, v1);
      if constexpr (FP16) {
        h2 hv = { (_Float16)v0, (_Float16)v1 };
        unsigned short* rn = (unsigned short*)rbuf + (size_t)((t + 1) & 1) * RD;
        *(unsigned int*)(rn + row0) = __builtin_bit_cast(unsigned int, hv);
      } else {
        float* rn = (float*)rbuf + (size_t)((t + 1) & 1) * RD;
        *(float2*)(rn + row0) = make_float2(v0, v1);
      }
    }
    __threadfence();
    grid.sync();
  }
}

extern "C" void kernel_launch(void* const* d_in, const int* in_sizes, int n_in,
                              void* d_out, int out_size, void* d_ws, size_t ws_size,
                              hipStream_t stream) {
  const float* in_seq    = (const float*)d_in[0];
  const float* res_state = (const float*)d_in[1];
  const float* W_in      = (const float*)d_in[2];
  const float* W_res     = (const float*)d_in[3];
  const float* b_res     = (const float*)d_in[4];
  float* out = (float*)d_out;

  // in_proj into d_out (consumed+overwritten in-place by the rollout)
  hipLaunchKernelGGL(in_proj_kernel, dim3(32, 128), dim3(256), 0, stream,
                     in_seq, W_in, b_res, out);

  const size_t w16_bytes = (size_t)RD * RD * 2;
  if (ws_size >= w16_bytes + 64 * 1024) {
    // fp16 weights in ws; r double-buffer behind them
    unsigned short* w16  = (unsigned short*)d_ws;
    unsigned short* rbuf = (unsigned short*)((char*)d_ws + w16_bytes);
    hipLaunchKernelGGL(cvt_w_kernel, dim3(8192), dim3(256), 0, stream,
                       W_res, w16, (long)RD * RD);
    hipLaunchKernelGGL(cvt_r16_kernel, dim3(RD / 256), dim3(256), 0, stream,
                       res_state, rbuf);
    const void* Wv = (const void*)w16;
    void* rv = (void*)rbuf;
    float* iov = out;
    void* args[3] = { &Wv, &rv, &iov };
    hipLaunchCooperativeKernel(rollout_kernel<true>, dim3(256), dim3(1024),
                               args, 0, stream);
  } else {
    // fallback: stream fp32 W_res straight from d_in; only r buffers in ws
    float* rbuf = (float*)d_ws;
    hipLaunchKernelGGL(cvt_r32_kernel, dim3(RD / 256), dim3(256), 0, stream,
                       res_state, rbuf);
    const void* Wv = (const void*)W_res;
    void* rv = (void*)rbuf;
    float* iov = out;
    void* args[3] = { &Wv, &rv, &iov };
    hipLaunchCooperativeKernel(rollout_kernel<false>, dim3(256), dim3(1024),
                               args, 0, stream);
  }
}

// Round 3
// 22772.444 us; speedup vs baseline: 6.9535x; 6.9535x over previous
//
#include <hip/hip_runtime.h>
#include <hip/hip_cooperative_groups.h>

typedef _Float16 h2 __attribute__((ext_vector_type(2)));
typedef float f2 __attribute__((ext_vector_type(2)));

static constexpr int T_LEN = 1024;
static constexpr int RD    = 8192;
static constexpr int SD    = 128;

// ---------- fdot2 wrapper: v_dot2_f32_f16 with scalar fallback ----------
__device__ __forceinline__ float dot2(unsigned int a, unsigned int b, float c) {
#if __has_builtin(__builtin_amdgcn_fdot2)
  return __builtin_amdgcn_fdot2(__builtin_bit_cast(h2, a), __builtin_bit_cast(h2, b), c, false);
#else
  h2 ha = __builtin_bit_cast(h2, a), hb = __builtin_bit_cast(h2, b);
  return c + (float)ha[0] * (float)hb[0] + (float)ha[1] * (float)hb[1];
#endif
}

// ---------- W_res fp32 -> fp16 (ushort bits), grid-stride float4 ----------
// nt loads: W_res fp32 (256 MB) is read exactly once — don't let it evict
// anything from L3. w16 writes stay normal (we WANT w16 resident in L3).
__global__ void cvt_w_kernel(const float* __restrict__ w, unsigned short* __restrict__ w16, long n) {
  long i = ((long)blockIdx.x * blockDim.x + threadIdx.x) * 4;
  long stride = (long)gridDim.x * blockDim.x * 4;
  for (; i < n; i += stride) {
    float f0 = __builtin_nontemporal_load(w + i);
    float f1 = __builtin_nontemporal_load(w + i + 1);
    float f2_ = __builtin_nontemporal_load(w + i + 2);
    float f3 = __builtin_nontemporal_load(w + i + 3);
    h2 p0 = { (_Float16)f0, (_Float16)f1 };
    h2 p1 = { (_Float16)f2_, (_Float16)f3 };
    uint2 o;
    o.x = __builtin_bit_cast(unsigned int, p0);
    o.y = __builtin_bit_cast(unsigned int, p1);
    *(uint2*)(w16 + i) = o;
  }
}

// ---------- r0 fp32 -> fp16, plus barrier zero-init ----------
__global__ void cvt_r16_kernel(const float* __restrict__ r, unsigned short* __restrict__ rh,
                               int* __restrict__ bar) {
  int i = blockIdx.x * 256 + threadIdx.x;
  _Float16 h = (_Float16)r[i];
  rh[i] = __builtin_bit_cast(unsigned short, h);
  if (blockIdx.x == 0 && threadIdx.x < 64) bar[threadIdx.x] = 0;
}

// ---------- r0 fp32 -> fp32 (fallback path), plus barrier zero-init ----------
__global__ void cvt_r32_kernel(const float* __restrict__ r, float* __restrict__ rf,
                               int* __restrict__ bar) {
  int i = blockIdx.x * 256 + threadIdx.x;
  rf[i] = r[i];
  if (blockIdx.x == 0 && threadIdx.x < 64) bar[threadIdx.x] = 0;
}

// ---------- in_proj = in_seq @ W_in^T + b_res, written into d_out ----------
__global__ void in_proj_kernel(const float* __restrict__ in_seq,  // 1024 x 128
                               const float* __restrict__ W_in,    // 8192 x 128
                               const float* __restrict__ b_res,   // 8192
                               float* __restrict__ out) {         // 1024 x 8192
  __shared__ float u[8 * SD];
  const int tid = threadIdx.x;
  const int ib = blockIdx.x;
  const int tb = blockIdx.y;
  ((float4*)u)[tid] = ((const float4*)(in_seq + (size_t)tb * 8 * SD))[tid];
  __syncthreads();
  const int i = ib * 256 + tid;
  const float4* wrow = (const float4*)(W_in + (size_t)i * SD);
  float b = b_res[i];
  float acc[8];
#pragma unroll
  for (int t = 0; t < 8; ++t) acc[t] = b;
  for (int kc = 0; kc < SD / 4; ++kc) {
    float4 w = wrow[kc];
#pragma unroll
    for (int t = 0; t < 8; ++t) {
      float4 uv = ((const float4*)(u + t * SD))[kc];
      acc[t] += w.x * uv.x + w.y * uv.y + w.z * uv.z + w.w * uv.w;
    }
  }
#pragma unroll
  for (int t = 0; t < 8; ++t)
    out[(size_t)(tb * 8 + t) * RD + i] = acc[t];
}

// ---------- lightweight device-wide barrier ----------
// bar[0] = monotonic arrive counter, bar[32] = generation (separate 128B lines).
__device__ __forceinline__ void grid_barrier(int* bar, int t, int nblk) {
  __syncthreads();
  if (threadIdx.x == 0) {
    int arrived = __hip_atomic_fetch_add(&bar[0], 1, __ATOMIC_RELEASE, __HIP_MEMORY_SCOPE_AGENT);
    int target = (t + 1) * nblk;
    if (arrived == target - 1) {
      __hip_atomic_store(&bar[32], t + 1, __ATOMIC_RELEASE, __HIP_MEMORY_SCOPE_AGENT);
    } else {
      while (__hip_atomic_load(&bar[32], __ATOMIC_RELAXED, __HIP_MEMORY_SCOPE_AGENT) <= t)
        __builtin_amdgcn_s_sleep(2);
    }
    // one acquire to invalidate L1/L2 so this CU sees remote r-writes
    (void)__hip_atomic_load(&bar[32], __ATOMIC_ACQUIRE, __HIP_MEMORY_SCOPE_AGENT);
  }
  __syncthreads();
}

// ---------- persistent rollout, 4-deep software-pipelined loads ----------
// 256 blocks x 1024 threads; block owns 32 rows, wave owns 2 adjacent rows.
template <bool FP16>
__global__ __launch_bounds__(1024, 4) void rollout_kernel(const void* __restrict__ Wv,
                                                          void* __restrict__ rbuf,
                                                          float* __restrict__ io,
                                                          int* __restrict__ bar) {
  const int lane = threadIdx.x & 63;
  const int wave = threadIdx.x >> 6;
  const int row0 = blockIdx.x * 32 + wave * 2;
  const int nblk = gridDim.x;

  for (int t = 0; t < T_LEN; ++t) {
    float a0 = 0.f, a1 = 0.f;
    if constexpr (FP16) {
      const uint4* w0 = (const uint4*)((const unsigned short*)Wv + (size_t)row0 * RD);
      const uint4* w1 = w0 + RD / 8;
      const uint4* rh = (const uint4*)((const unsigned short*)rbuf + (size_t)(t & 1) * RD);
      uint4 wa[4], wb[4], rv[4];
#pragma unroll
      for (int k = 0; k < 4; ++k) {
        int idx = k * 64 + lane;
        rv[k] = rh[idx]; wa[k] = w0[idx]; wb[k] = w1[idx];
      }
#pragma unroll
      for (int j = 0; j < 16; ++j) {
        int k = j & 3;
        uint4 A = wa[k], B = wb[k], R = rv[k];
        if (j < 12) {
          int idx = (j + 4) * 64 + lane;
          rv[k] = rh[idx]; wa[k] = w0[idx]; wb[k] = w1[idx];
        }
        a0 = dot2(A.x, R.x, a0); a0 = dot2(A.y, R.y, a0);
        a0 = dot2(A.z, R.z, a0); a0 = dot2(A.w, R.w, a0);
        a1 = dot2(B.x, R.x, a1); a1 = dot2(B.y, R.y, a1);
        a1 = dot2(B.z, R.z, a1); a1 = dot2(B.w, R.w, a1);
      }
    } else {
      const float4* w0 = (const float4*)((const float*)Wv + (size_t)row0 * RD);
      const float4* w1 = w0 + RD / 4;
      const float4* rf = (const float4*)((const float*)rbuf + (size_t)(t & 1) * RD);
      float4 wa[4], wb[4], rv[4];
#pragma unroll
      for (int k = 0; k < 4; ++k) {
        int idx = k * 64 + lane;
        rv[k] = rf[idx]; wa[k] = w0[idx]; wb[k] = w1[idx];
      }
#pragma unroll
      for (int j = 0; j < 32; ++j) {
        int k = j & 3;
        float4 A = wa[k], B = wb[k], R = rv[k];
        if (j < 28) {
          int idx = (j + 4) * 64 + lane;
          rv[k] = rf[idx]; wa[k] = w0[idx]; wb[k] = w1[idx];
        }
        a0 += A.x * R.x + A.y * R.y + A.z * R.z + A.w * R.w;
        a1 += B.x * R.x + B.y * R.y + B.z * R.z + B.w * R.w;
      }
    }
#pragma unroll
    for (int off = 32; off; off >>= 1) {
      a0 += __shfl_xor(a0, off);
      a1 += __shfl_xor(a1, off);
    }
    if (lane == 0) {
      float2 p = *(const float2*)(io + (size_t)t * RD + row0);
      float v0 = tanhf(a0 + p.x);
      float v1 = tanhf(a1 + p.y);
      // nt store: res_seq is written once, never re-read — keep it out of L3
      f2 vv = { v0, v1 };
      __builtin_nontemporal_store(vv, (f2*)(io + (size_t)t * RD + row0));
      if constexpr (FP16) {
        h2 hv = { (_Float16)v0, (_Float16)v1 };
        unsigned short* rn = (unsigned short*)rbuf + (size_t)((t + 1) & 1) * RD;
        *(unsigned int*)(rn + row0) = __builtin_bit_cast(unsigned int, hv);
      } else {
        float* rn = (float*)rbuf + (size_t)((t + 1) & 1) * RD;
        f2 fv = { v0, v1 };
        *(f2*)(rn + row0) = fv;
      }
    }
    grid_barrier(bar, t, nblk);
  }
}

extern "C" void kernel_launch(void* const* d_in, const int* in_sizes, int n_in,
                              void* d_out, int out_size, void* d_ws, size_t ws_size,
                              hipStream_t stream) {
  const float* in_seq    = (const float*)d_in[0];
  const float* res_state = (const float*)d_in[1];
  const float* W_in      = (const float*)d_in[2];
  const float* W_res     = (const float*)d_in[3];
  const float* b_res     = (const float*)d_in[4];
  float* out = (float*)d_out;

  // in_proj into d_out (consumed+overwritten in-place by the rollout)
  hipLaunchKernelGGL(in_proj_kernel, dim3(32, 128), dim3(256), 0, stream,
                     in_seq, W_in, b_res, out);

  const size_t w16_bytes = (size_t)RD * RD * 2;
  const size_t rbuf16_bytes = (size_t)2 * RD * 2;
  if (ws_size >= w16_bytes + rbuf16_bytes + 4096) {
    unsigned short* w16  = (unsigned short*)d_ws;
    unsigned short* rbuf = (unsigned short*)((char*)d_ws + w16_bytes);
    int* bar = (int*)((char*)d_ws + w16_bytes + rbuf16_bytes);
    hipLaunchKernelGGL(cvt_w_kernel, dim3(8192), dim3(256), 0, stream,
                       W_res, w16, (long)RD * RD);
    hipLaunchKernelGGL(cvt_r16_kernel, dim3(RD / 256), dim3(256), 0, stream,
                       res_state, rbuf, bar);
    const void* Wv = (const void*)w16;
    void* rv = (void*)rbuf;
    float* iov = out;
    int* barv = bar;
    void* args[4] = { &Wv, &rv, &iov, &barv };
    (void)hipLaunchCooperativeKernel(rollout_kernel<true>, dim3(256), dim3(1024),
                                     args, 0, stream);
  } else {
    float* rbuf = (float*)d_ws;
    int* bar = (int*)((char*)d_ws + (size_t)2 * RD * 4);
    hipLaunchKernelGGL(cvt_r32_kernel, dim3(RD / 256), dim3(256), 0, stream,
                       res_state, rbuf, bar);
    const void* Wv = (const void*)W_res;
    void* rv = (void*)rbuf;
    float* iov = out;
    int* barv = bar;
    void* args[4] = { &Wv, &rv, &iov, &barv };
    (void)hipLaunchCooperativeKernel(rollout_kernel<false>, dim3(256), dim3(1024),
                                     args, 0, stream);
  }
}

// Round 4
// 16183.551 us; speedup vs baseline: 9.7845x; 1.4071x over previous
//
#include <hip/hip_runtime.h>

typedef _Float16 h2 __attribute__((ext_vector_type(2)));
typedef float f2 __attribute__((ext_vector_type(2)));

static constexpr int T_LEN = 1024;
static constexpr int RD    = 8192;
static constexpr int SD    = 128;
static constexpr int NBLK  = 256;
static constexpr int GRPS  = 8;
static constexpr int BLK_PER_GRP = NBLK / GRPS;  // 32
// bar layout (ints): group g arrive @ [g*16], super @ [128], generation @ [160]

// ---------- fdot2 wrapper ----------
__device__ __forceinline__ float dot2(unsigned int a, unsigned int b, float c) {
#if __has_builtin(__builtin_amdgcn_fdot2)
  return __builtin_amdgcn_fdot2(__builtin_bit_cast(h2, a), __builtin_bit_cast(h2, b), c, false);
#else
  h2 ha = __builtin_bit_cast(h2, a), hb = __builtin_bit_cast(h2, b);
  return c + (float)ha[0] * (float)hb[0] + (float)ha[1] * (float)hb[1];
#endif
}

// ---------- W_res fp32 -> fp16 ----------
__global__ void cvt_w_kernel(const float* __restrict__ w, unsigned short* __restrict__ w16, long n) {
  long i = ((long)blockIdx.x * blockDim.x + threadIdx.x) * 4;
  long stride = (long)gridDim.x * blockDim.x * 4;
  for (; i < n; i += stride) {
    float f0 = __builtin_nontemporal_load(w + i);
    float f1 = __builtin_nontemporal_load(w + i + 1);
    float f2_ = __builtin_nontemporal_load(w + i + 2);
    float f3 = __builtin_nontemporal_load(w + i + 3);
    h2 p0 = { (_Float16)f0, (_Float16)f1 };
    h2 p1 = { (_Float16)f2_, (_Float16)f3 };
    uint2 o;
    o.x = __builtin_bit_cast(unsigned int, p0);
    o.y = __builtin_bit_cast(unsigned int, p1);
    *(uint2*)(w16 + i) = o;
  }
}

// ---------- r0 fp32 -> fp16 slot 0, zero barrier block ----------
__global__ void cvt_r16_kernel(const float* __restrict__ r, unsigned short* __restrict__ rh,
                               int* __restrict__ bar) {
  int i = blockIdx.x * 256 + threadIdx.x;
  _Float16 h = (_Float16)r[i];
  rh[i] = __builtin_bit_cast(unsigned short, h);
  if (blockIdx.x == 0) bar[threadIdx.x] = 0;
}

// ---------- r0 fp32 -> fp32 (fallback), zero barrier ----------
__global__ void cvt_r32_kernel(const float* __restrict__ r, float* __restrict__ rf,
                               int* __restrict__ bar) {
  int i = blockIdx.x * 256 + threadIdx.x;
  rf[i] = r[i];
  if (blockIdx.x == 0) bar[threadIdx.x] = 0;
}

// ---------- in_proj = in_seq @ W_in^T + b_res -> d_out ----------
__global__ void in_proj_kernel(const float* __restrict__ in_seq,
                               const float* __restrict__ W_in,
                               const float* __restrict__ b_res,
                               float* __restrict__ out) {
  __shared__ float u[8 * SD];
  const int tid = threadIdx.x;
  const int ib = blockIdx.x;
  const int tb = blockIdx.y;
  ((float4*)u)[tid] = ((const float4*)(in_seq + (size_t)tb * 8 * SD))[tid];
  __syncthreads();
  const int i = ib * 256 + tid;
  const float4* wrow = (const float4*)(W_in + (size_t)i * SD);
  float b = b_res[i];
  float acc[8];
#pragma unroll
  for (int t = 0; t < 8; ++t) acc[t] = b;
  for (int kc = 0; kc < SD / 4; ++kc) {
    float4 w = wrow[kc];
#pragma unroll
    for (int t = 0; t < 8; ++t) {
      float4 uv = ((const float4*)(u + t * SD))[kc];
      acc[t] += w.x * uv.x + w.y * uv.y + w.z * uv.z + w.w * uv.w;
    }
  }
#pragma unroll
  for (int t = 0; t < 8; ++t)
    out[(size_t)(tb * 8 + t) * RD + i] = acc[t];
}

// ---------- main rollout ----------
// MULTI=true : rseq has T_LEN+1 slots; r exchange via sc1 relaxed atomics +
//              cold-line freshness — NO acquire/inv, W stays warm in L2.
// MULTI=false: 2-slot rseq, wave0 does an agent-acquire each step (round-3 style).
template <bool MULTI>
__global__ __launch_bounds__(1024, 4) void rollout_kernel(
    const unsigned short* __restrict__ W, unsigned short* __restrict__ rseq,
    float* __restrict__ io, int* __restrict__ bar) {
  __shared__ int lds_cnt;
  const int lane = threadIdx.x & 63;
  const int wave = threadIdx.x >> 6;
  const int row0 = blockIdx.x * 32 + wave * 2;
  if (threadIdx.x == 0) lds_cnt = 0;
  __syncthreads();

  const uint4* w0 = (const uint4*)(W + (size_t)row0 * RD);
  const uint4* w1 = w0 + RD / 8;

  uint4 wa[4], wb[4], rv[4];
#pragma unroll
  for (int k = 0; k < 4; ++k) {          // initial W prefetch, iters 0..3
    int idx = k * 64 + lane;
    wa[k] = w0[idx]; wb[k] = w1[idx];
  }

#pragma unroll 1
  for (int t = 0; t < T_LEN; ++t) {
    const uint4* rh = (const uint4*)(rseq + (size_t)(MULTI ? t : (t & 1)) * RD);
#pragma unroll
    for (int k = 0; k < 4; ++k) rv[k] = rh[k * 64 + lane];   // r preamble
    float a0 = 0.f, a1 = 0.f;
#pragma unroll
    for (int j = 0; j < 16; ++j) {
      int k = j & 3;
      uint4 A = wa[k], B = wb[k], R = rv[k];
      if (j < 12) {
        int idx = (j + 4) * 64 + lane;
        rv[k] = rh[idx]; wa[k] = w0[idx]; wb[k] = w1[idx];
      }
      a0 = dot2(A.x, R.x, a0); a0 = dot2(A.y, R.y, a0);
      a0 = dot2(A.z, R.z, a0); a0 = dot2(A.w, R.w, a0);
      a1 = dot2(B.x, R.x, a1); a1 = dot2(B.y, R.y, a1);
      a1 = dot2(B.z, R.z, a1); a1 = dot2(B.w, R.w, a1);
    }
#pragma unroll
    for (int off = 32; off; off >>= 1) {
      a0 += __shfl_xor(a0, off);
      a1 += __shfl_xor(a1, off);
    }
    if (lane == 0) {
      float2 p = *(const float2*)(io + (size_t)t * RD + row0);
      float v0 = tanhf(a0 + p.x);
      float v1 = tanhf(a1 + p.y);
      f2 vv = { v0, v1 };
      __builtin_nontemporal_store(vv, (f2*)(io + (size_t)t * RD + row0));
      h2 hv = { (_Float16)v0, (_Float16)v1 };
      unsigned int bits = __builtin_bit_cast(unsigned int, hv);
      unsigned int* rdst = (unsigned int*)(rseq + (size_t)(MULTI ? (t + 1) : ((t + 1) & 1)) * RD + row0);
      __hip_atomic_store(rdst, bits, __ATOMIC_RELAXED, __HIP_MEMORY_SCOPE_AGENT);
    }
    asm volatile("" ::: "memory");
    __builtin_amdgcn_s_waitcnt(0x0F70);   // vmcnt(0): r-store at coherence point
    asm volatile("" ::: "memory");
    if (lane == 0) {
      int old = __hip_atomic_fetch_add(&lds_cnt, 1, __ATOMIC_RELAXED, __HIP_MEMORY_SCOPE_WORKGROUP);
      if (old == (t + 1) * 16 - 1) {      // last wave of block this step
        int g = blockIdx.x >> 5;
        int go = __hip_atomic_fetch_add(&bar[g * 16], 1, __ATOMIC_RELAXED, __HIP_MEMORY_SCOPE_AGENT);
        if (go == (t + 1) * BLK_PER_GRP - 1) {
          int so = __hip_atomic_fetch_add(&bar[128], 1, __ATOMIC_RELAXED, __HIP_MEMORY_SCOPE_AGENT);
          if (so == (t + 1) * GRPS - 1) {
            __hip_atomic_store(&bar[160], t + 1, __ATOMIC_RELAXED, __HIP_MEMORY_SCOPE_AGENT);
          }
        }
      }
    }
    if (wave != 0) {
      // next-step W prefetch (same addresses every step) in flight across the spin
#pragma unroll
      for (int k = 0; k < 4; ++k) {
        int idx = k * 64 + lane;
        wa[k] = w0[idx]; wb[k] = w1[idx];
      }
      asm volatile("" ::: "memory");
      __builtin_amdgcn_s_barrier();
      asm volatile("" ::: "memory");
    } else {
      if (lane == 0) {
        while (__hip_atomic_load(&bar[160], __ATOMIC_RELAXED, __HIP_MEMORY_SCOPE_AGENT) <= t)
          __builtin_amdgcn_s_sleep(2);
        if (!MULTI)
          (void)__hip_atomic_load(&bar[160], __ATOMIC_ACQUIRE, __HIP_MEMORY_SCOPE_AGENT);
      }
      asm volatile("" ::: "memory");
      __builtin_amdgcn_s_barrier();
      asm volatile("" ::: "memory");
#pragma unroll
      for (int k = 0; k < 4; ++k) {
        int idx = k * 64 + lane;
        wa[k] = w0[idx]; wb[k] = w1[idx];
      }
    }
  }
}

// ---------- fp32 fallback (tiny ws; round-3 proven structure) ----------
__device__ __forceinline__ void grid_barrier_f32(int* bar, int t, int nblk) {
  __syncthreads();
  if (threadIdx.x == 0) {
    int arrived = __hip_atomic_fetch_add(&bar[0], 1, __ATOMIC_RELEASE, __HIP_MEMORY_SCOPE_AGENT);
    if (arrived == (t + 1) * nblk - 1) {
      __hip_atomic_store(&bar[32], t + 1, __ATOMIC_RELEASE, __HIP_MEMORY_SCOPE_AGENT);
    } else {
      while (__hip_atomic_load(&bar[32], __ATOMIC_RELAXED, __HIP_MEMORY_SCOPE_AGENT) <= t)
        __builtin_amdgcn_s_sleep(2);
    }
    (void)__hip_atomic_load(&bar[32], __ATOMIC_ACQUIRE, __HIP_MEMORY_SCOPE_AGENT);
  }
  __syncthreads();
}

__global__ __launch_bounds__(1024, 4) void rollout_f32(const float* __restrict__ W,
                                                       float* __restrict__ rbuf,
                                                       float* __restrict__ io,
                                                       int* __restrict__ bar) {
  const int lane = threadIdx.x & 63;
  const int wave = threadIdx.x >> 6;
  const int row0 = blockIdx.x * 32 + wave * 2;
  const int nblk = gridDim.x;
  for (int t = 0; t < T_LEN; ++t) {
    float a0 = 0.f, a1 = 0.f;
    const float4* w0 = (const float4*)(W + (size_t)row0 * RD);
    const float4* w1 = w0 + RD / 4;
    const float4* rf = (const float4*)(rbuf + (size_t)(t & 1) * RD);
    float4 wa[4], wb[4], rv[4];
#pragma unroll
    for (int k = 0; k < 4; ++k) {
      int idx = k * 64 + lane;
      rv[k] = rf[idx]; wa[k] = w0[idx]; wb[k] = w1[idx];
    }
#pragma unroll
    for (int j = 0; j < 32; ++j) {
      int k = j & 3;
      float4 A = wa[k], B = wb[k], R = rv[k];
      if (j < 28) {
        int idx = (j + 4) * 64 + lane;
        rv[k] = rf[idx]; wa[k] = w0[idx]; wb[k] = w1[idx];
      }
      a0 += A.x * R.x + A.y * R.y + A.z * R.z + A.w * R.w;
      a1 += B.x * R.x + B.y * R.y + B.z * R.z + B.w * R.w;
    }
#pragma unroll
    for (int off = 32; off; off >>= 1) {
      a0 += __shfl_xor(a0, off);
      a1 += __shfl_xor(a1, off);
    }
    if (lane == 0) {
      float2 p = *(const float2*)(io + (size_t)t * RD + row0);
      float v0 = tanhf(a0 + p.x);
      float v1 = tanhf(a1 + p.y);
      f2 vv = { v0, v1 };
      __builtin_nontemporal_store(vv, (f2*)(io + (size_t)t * RD + row0));
      float* rn = rbuf + (size_t)((t + 1) & 1) * RD;
      *(f2*)(rn + row0) = vv;
    }
    grid_barrier_f32(bar, t, nblk);
  }
}

extern "C" void kernel_launch(void* const* d_in, const int* in_sizes, int n_in,
                              void* d_out, int out_size, void* d_ws, size_t ws_size,
                              hipStream_t stream) {
  const float* in_seq    = (const float*)d_in[0];
  const float* res_state = (const float*)d_in[1];
  const float* W_in      = (const float*)d_in[2];
  const float* W_res     = (const float*)d_in[3];
  const float* b_res     = (const float*)d_in[4];
  float* out = (float*)d_out;

  hipLaunchKernelGGL(in_proj_kernel, dim3(32, 128), dim3(256), 0, stream,
                     in_seq, W_in, b_res, out);

  const size_t w16_bytes   = (size_t)RD * RD * 2;                 // 128 MB
  const size_t rseq_multi  = (size_t)(T_LEN + 1) * RD * 2;        // 16.8 MB
  const size_t rseq_double = (size_t)2 * RD * 2;
  const size_t bar_bytes   = 1024 * 4;

  if (ws_size >= w16_bytes + rseq_multi + bar_bytes) {
    unsigned short* w16  = (unsigned short*)d_ws;
    unsigned short* rseq = (unsigned short*)((char*)d_ws + w16_bytes);
    int* bar = (int*)((char*)d_ws + w16_bytes + rseq_multi);
    hipLaunchKernelGGL(cvt_w_kernel, dim3(8192), dim3(256), 0, stream,
                       W_res, w16, (long)RD * RD);
    hipLaunchKernelGGL(cvt_r16_kernel, dim3(RD / 256), dim3(256), 0, stream,
                       res_state, rseq, bar);
    const unsigned short* Wv = w16;
    unsigned short* rv = rseq;
    float* iov = out;
    int* barv = bar;
    void* args[4] = { &Wv, &rv, &iov, &barv };
    (void)hipLaunchCooperativeKernel(rollout_kernel<true>, dim3(NBLK), dim3(1024),
                                     args, 0, stream);
  } else if (ws_size >= w16_bytes + rseq_double + bar_bytes) {
    unsigned short* w16  = (unsigned short*)d_ws;
    unsigned short* rseq = (unsigned short*)((char*)d_ws + w16_bytes);
    int* bar = (int*)((char*)d_ws + w16_bytes + rseq_double);
    hipLaunchKernelGGL(cvt_w_kernel, dim3(8192), dim3(256), 0, stream,
                       W_res, w16, (long)RD * RD);
    hipLaunchKernelGGL(cvt_r16_kernel, dim3(RD / 256), dim3(256), 0, stream,
                       res_state, rseq, bar);
    const unsigned short* Wv = w16;
    unsigned short* rv = rseq;
    float* iov = out;
    int* barv = bar;
    void* args[4] = { &Wv, &rv, &iov, &barv };
    (void)hipLaunchCooperativeKernel(rollout_kernel<false>, dim3(NBLK), dim3(1024),
                                     args, 0, stream);
  } else {
    float* rbuf = (float*)d_ws;
    int* bar = (int*)((char*)d_ws + (size_t)2 * RD * 4);
    hipLaunchKernelGGL(cvt_r32_kernel, dim3(RD / 256), dim3(256), 0, stream,
                       res_state, rbuf, bar);
    const float* Wv = W_res;
    float* rv = rbuf;
    float* iov = out;
    int* barv = bar;
    void* args[4] = { &Wv, &rv, &iov, &barv };
    (void)hipLaunchCooperativeKernel(rollout_f32, dim3(NBLK), dim3(1024),
                                     args, 0, stream);
  }
}